// Round 6
// baseline (284.343 us; speedup 1.0000x reference)
//
#include <hip/hip_runtime.h>
#include <stdint.h>
#include <stddef.h>

#define L_SEQ 16384
#define H_DIM 1024
#define P_DIM 512
#define N2P   1024
#define CHUNK 64
#define NCH   256   // L_SEQ / CHUNK

// merged pack-kernel block ranges
#define NB_U 8192   // L*H/(256*8)
#define NB_B 256    // P*H/(256*8)   -- vectorized 8 elems/thread
#define NB_C 512    // H*2P/(256*8)  -- vectorized 8 outs/thread
#define NB_T 2      // lambda tables + cnt reset

typedef __bf16 bf16x8 __attribute__((ext_vector_type(8)));
typedef float  f32x4  __attribute__((ext_vector_type(4)));
typedef unsigned short u16x8 __attribute__((ext_vector_type(8)));
typedef unsigned int   u32x4 __attribute__((ext_vector_type(4)));

__device__ __forceinline__ unsigned short f2bf(float x) {
  unsigned int u = __float_as_uint(x);
  u += 0x7FFFu + ((u >> 16) & 1u);   // round-to-nearest-even
  return (unsigned short)(u >> 16);
}
__device__ __forceinline__ float bf2f(unsigned short x) {
  return __uint_as_float((unsigned int)x << 16);
}

// ---------------------------------------------------------------------------
// Merged pack: [0,NB_U) u->bf16 cast; [NB_U,+NB_B) B_bar pack; then C pack;
// then lambda tables + scan-counter reset. All branches are block-uniform.
// Bp (2P,H): row 2p=Re, 2p+1=Im.  Cp (H,2P): col 2p=C_re, 2p+1=-C_im.
// ---------------------------------------------------------------------------
__global__ void k_pack_all(const float* __restrict__ U, unsigned short* __restrict__ Ub,
                           const float* __restrict__ Bre, const float* __restrict__ Bim,
                           unsigned short* __restrict__ Bp,
                           const float* __restrict__ Cre, const float* __restrict__ Cim,
                           unsigned short* __restrict__ Cp,
                           const float* __restrict__ Lre, const float* __restrict__ Lim,
                           const float* __restrict__ lstep,
                           float2* __restrict__ lam, float2* __restrict__ lamK,
                           int* __restrict__ cnt) {
  int bid = blockIdx.x, tid = threadIdx.x;
  if (bid < NB_U) {
    size_t base = ((size_t)bid * 256 + tid) * 8;
    const float4* s = (const float4*)(U + base);
    float4 v0 = s[0], v1 = s[1];
    u16x8 o;
    o[0] = f2bf(v0.x); o[1] = f2bf(v0.y); o[2] = f2bf(v0.z); o[3] = f2bf(v0.w);
    o[4] = f2bf(v1.x); o[5] = f2bf(v1.y); o[6] = f2bf(v1.z); o[7] = f2bf(v1.w);
    *(u16x8*)(Ub + base) = o;
  } else if (bid < NB_U + NB_B) {
    // 8 elems/thread; base multiple of 8, so p = base>>10 is wave-uniform
    int base = ((bid - NB_U) * 256 + tid) * 8;       // < P*H
    int p = base >> 10, h = base & 1023;
    float sv, cv;
    float step = expf(lstep[p]);
    float ar = Lre[p] * step, ai = Lim[p] * step;
    float er = expf(ar);
    sincosf(ai, &sv, &cv);
    float lr = er * cv, li = er * sv;
    float nr = lr - 1.0f, ni = li;
    float dr = Lre[p], di = Lim[p];
    float den = dr * dr + di * di;
    float cx = (nr * dr + ni * di) / den;
    float cy = (ni * dr - nr * di) / den;
    const float4* sre = (const float4*)(Bre + base);
    const float4* sim = (const float4*)(Bim + base);
    float4 r0 = sre[0], r1 = sre[1], i0 = sim[0], i1 = sim[1];
    u16x8 ore, oim;
    ore[0] = f2bf(cx * r0.x - cy * i0.x);  oim[0] = f2bf(cx * i0.x + cy * r0.x);
    ore[1] = f2bf(cx * r0.y - cy * i0.y);  oim[1] = f2bf(cx * i0.y + cy * r0.y);
    ore[2] = f2bf(cx * r0.z - cy * i0.z);  oim[2] = f2bf(cx * i0.z + cy * r0.z);
    ore[3] = f2bf(cx * r0.w - cy * i0.w);  oim[3] = f2bf(cx * i0.w + cy * r0.w);
    ore[4] = f2bf(cx * r1.x - cy * i1.x);  oim[4] = f2bf(cx * i1.x + cy * r1.x);
    ore[5] = f2bf(cx * r1.y - cy * i1.y);  oim[5] = f2bf(cx * i1.y + cy * r1.y);
    ore[6] = f2bf(cx * r1.z - cy * i1.z);  oim[6] = f2bf(cx * i1.z + cy * r1.z);
    ore[7] = f2bf(cx * r1.w - cy * i1.w);  oim[7] = f2bf(cx * i1.w + cy * r1.w);
    *(u16x8*)(Bp + (size_t)(2 * p) * H_DIM + h)     = ore;
    *(u16x8*)(Bp + (size_t)(2 * p + 1) * H_DIM + h) = oim;
  } else if (bid < NB_U + NB_B + NB_C) {
    // 8 outputs/thread: row h of Cp, cols j0..j0+7 = p0..p0+3 interleaved re/-im
    int base = ((bid - NB_U - NB_B) * 256 + tid) * 8; // < H*2P
    int h = base >> 10, j0 = base & 1023;
    int p0 = j0 >> 1;                                 // multiple of 4
    float4 cr = *(const float4*)(Cre + (size_t)h * P_DIM + p0);
    float4 ci = *(const float4*)(Cim + (size_t)h * P_DIM + p0);
    u16x8 o;
    o[0] = f2bf(cr.x); o[1] = f2bf(-ci.x);
    o[2] = f2bf(cr.y); o[3] = f2bf(-ci.y);
    o[4] = f2bf(cr.z); o[5] = f2bf(-ci.z);
    o[6] = f2bf(cr.w); o[7] = f2bf(-ci.w);
    *(u16x8*)(Cp + base) = o;
  } else {
    int p = (bid - NB_U - NB_B - NB_C) * 256 + tid;
    if (p < P_DIM) {
      double step = exp((double)lstep[p]);
      double ar = (double)Lre[p] * step, ai = (double)Lim[p] * step;
      double er = exp(ar);
      lam[p] = make_float2((float)(er * cos(ai)), (float)(er * sin(ai)));
      double ka = (double)CHUNK * ai, kr = exp((double)CHUNK * ar);
      lamK[p] = make_float2((float)(kr * cos(ka)), (float)(kr * sin(ka)));
    }
    if (p == 0) {  // reset decoupled-lookback counters each iteration
      __hip_atomic_store(&cnt[0], 0, __ATOMIC_RELAXED, __HIP_MEMORY_SCOPE_AGENT);
      __hip_atomic_store(&cnt[1], 0, __ATOMIC_RELAXED, __HIP_MEMORY_SCOPE_AGENT);
    }
  }
}

// ---------------------------------------------------------------------------
// GEMM: out(M,N) = A(M,K) @ B(N,K)^T, bf16 in. 128x128 tile, BK=64, 4 waves,
// 4x4 mfma_f32_16x16x32_bf16. Grid (M/128, N/128), blockIdx.x fastest =>
// all N-tiles of an M-panel on the same XCD (A-panel fetched once per chip).
// LDS XOR swizzle (row&7) on the 8-elem column group kills the 16-way bank
// aliasing of the plain BK=64 layout. [reg-staged A-cast fusion reverted:
// measured 77 us vs 46 us DMA — m151's reg-staging penalty, confirmed]
// OUT=0: bf16 store. OUT=1: fp32 store, fused 2*acc + Dv[col]*bf2f(Ub).
// ---------------------------------------------------------------------------
template <int OUT>
__global__ void gemm_bt(const unsigned short* __restrict__ A,
                        const unsigned short* __restrict__ B,
                        void* __restrict__ Cout,
                        const unsigned short* __restrict__ Ub,
                        const float* __restrict__ Dv) {
  const int K = 1024, N = 1024;
  __shared__ unsigned short sA[128 * 64];
  __shared__ unsigned short sB[128 * 64];
  const int tid = threadIdx.x;
  const int wave = tid >> 6, lane = tid & 63;
  const int quad = lane >> 4, l16 = lane & 15;
  const int m0 = blockIdx.x * 128, n0 = blockIdx.y * 128;
  const int wm = (wave & 1) * 64, wn = (wave >> 1) * 64;

  f32x4 acc[4][4] = {};

  for (int kt = 0; kt < K; kt += 64) {
    __syncthreads();
#pragma unroll
    for (int r = 0; r < 4; ++r) {
      int s = r * 256 + tid;                   // LDS slot = staging index
      int row = s >> 3;
      int j8 = (s & 7) ^ (row & 7);            // swizzled global column-group
      const unsigned short* ga = A + (size_t)(m0 + row) * K + kt + j8 * 8;
      const unsigned short* gb = B + (size_t)(n0 + row) * K + kt + j8 * 8;
      __builtin_amdgcn_global_load_lds(
          (const __attribute__((address_space(1))) unsigned int*)ga,
          (__attribute__((address_space(3))) unsigned int*)(sA + (r * 256 + wave * 64) * 8),
          16, 0, 0);
      __builtin_amdgcn_global_load_lds(
          (const __attribute__((address_space(1))) unsigned int*)gb,
          (__attribute__((address_space(3))) unsigned int*)(sB + (r * 256 + wave * 64) * 8),
          16, 0, 0);
    }
    __syncthreads();

#pragma unroll
    for (int h = 0; h < 2; ++h) {
      bf16x8 af[4], bfr[4];
#pragma unroll
      for (int i = 0; i < 4; ++i) {
        int ra = wm + i * 16 + l16;
        af[i] = *(const bf16x8*)(sA + ra * 64 + (((h << 2) + quad) ^ (ra & 7)) * 8);
      }
#pragma unroll
      for (int j = 0; j < 4; ++j) {
        int rb = wn + j * 16 + l16;
        bfr[j] = *(const bf16x8*)(sB + rb * 64 + (((h << 2) + quad) ^ (rb & 7)) * 8);
      }
#pragma unroll
      for (int i = 0; i < 4; ++i)
#pragma unroll
        for (int j = 0; j < 4; ++j)
          acc[i][j] = __builtin_amdgcn_mfma_f32_16x16x32_bf16(af[i], bfr[j], acc[i][j], 0, 0, 0);
    }
  }

#pragma unroll
  for (int i = 0; i < 4; ++i) {
#pragma unroll
    for (int j = 0; j < 4; ++j) {
      int col = n0 + wn + j * 16 + l16;
#pragma unroll
      for (int r = 0; r < 4; ++r) {
        int row = m0 + wm + i * 16 + quad * 4 + r;
        size_t o = (size_t)row * N + col;
        float v = acc[i][j][r];
        if (OUT) {
          float u = bf2f(Ub[o]);
          ((float*)Cout)[o] = 2.0f * v + Dv[col] * u;
        } else {
          ((unsigned short*)Cout)[o] = f2bf(v);
        }
      }
    }
  }
}

// ---------------------------------------------------------------------------
// Merged scan (was scanA + scanC): single-counter decoupled lookback.
// Per (chunk,half) block: stage Bu tile ONCE, pass-1 unseeded chunk-sum,
// publish csum via agent-scope atomics + release fetch_add on cnt[half],
// tid0 spins until all NCH chunks published (publish happens before any
// spin => deadlock-free; 512 blocks x 64KB LDS = exactly 2/CU x 256 CU
// co-resident by capacity), Horner lookback (identical to old scanC),
// pass-2 seeded scan (bit-identical numerics), pack bf16 in place, store.
// Saves: 33.5 MB HBM re-read of Bu, one launch, one redundant scan pass.
// csum accessed with agent-scope atomics: plain loads could hit stale
// prior-iteration lines in the reader XCD's L2.
// ---------------------------------------------------------------------------
__global__ __launch_bounds__(256) void k_scan(const unsigned short* __restrict__ Bu,
                                              const float2* __restrict__ lam,
                                              const float2* __restrict__ lamK,
                                              unsigned long long* __restrict__ csum,
                                              int* __restrict__ cnt,
                                              unsigned short* __restrict__ xs) {
  __shared__ unsigned int tile[CHUNK * 256];   // 64 KB
  const int bid = blockIdx.x;                  // NCH*2 blocks
  const int chunk = bid >> 1, half = bid & 1;
  const int tid = threadIdx.x, wave = tid >> 6, lane = tid & 63;
  const unsigned int* gbase =
      (const unsigned int*)(Bu + (size_t)chunk * CHUNK * N2P) + half * 256;
#pragma unroll
  for (int r = 0; r < 16; ++r) {
    int row = r * 4 + wave;
    __builtin_amdgcn_global_load_lds(
        (const __attribute__((address_space(1))) unsigned int*)
            (gbase + (size_t)row * (N2P / 2) + lane * 4),
        (__attribute__((address_space(3))) unsigned int*)(tile + row * 256),
        16, 0, 0);
  }
  __syncthreads();
  const int p = half * 256 + tid;
  const float2 l = lam[p];

  // pass 1: unseeded chunk-sum (registers only; tile keeps original Bu)
  float sr = 0.f, si = 0.f;
#pragma unroll 16
  for (int t = 0; t < CHUNK; ++t) {
    unsigned int v = tile[t * 256 + tid];
    float br = bf2f((unsigned short)(v & 0xffffu));
    float bi = bf2f((unsigned short)(v >> 16));
    float nr = fmaf(l.x, sr, fmaf(-l.y, si, br));
    float ni = fmaf(l.x, si, fmaf(l.y, sr, bi));
    sr = nr; si = ni;
  }

  // publish csum[chunk][p] (device-coherent), then count this chunk done
  union { float2 f; unsigned long long u; } pub;
  pub.f = make_float2(sr, si);
  __hip_atomic_store(&csum[(size_t)chunk * P_DIM + p], pub.u,
                     __ATOMIC_RELAXED, __HIP_MEMORY_SCOPE_AGENT);
  __syncthreads();   // vmcnt drain: all 256 stores complete before the flag
  if (tid == 0) {
    __threadfence();
    __hip_atomic_fetch_add(&cnt[half], 1, __ATOMIC_RELEASE, __HIP_MEMORY_SCOPE_AGENT);
  }

  // spin until all chunks of this half are published, then Horner lookback
  float cr = 0.f, ci = 0.f;
  if (chunk > 0) {
    if (tid == 0) {
      while (__hip_atomic_load(&cnt[half], __ATOMIC_ACQUIRE, __HIP_MEMORY_SCOPE_AGENT) < NCH) {
        __builtin_amdgcn_s_sleep(2);
      }
    }
    __syncthreads();
    const float2 lk = lamK[p];
#pragma unroll 4
    for (int j = 0; j < chunk; ++j) {
      union { float2 f; unsigned long long u; } s;
      s.u = __hip_atomic_load(&csum[(size_t)j * P_DIM + p],
                              __ATOMIC_RELAXED, __HIP_MEMORY_SCOPE_AGENT);
      float nr = fmaf(lk.x, cr, fmaf(-lk.y, ci, s.f.x));
      float ni = fmaf(lk.x, ci, fmaf(lk.y, cr, s.f.y));
      cr = nr; ci = ni;
    }
  }

  // pass 2: seeded scan (identical to old scanC), pack bf16 in place
  float xr = cr, xi = ci;
#pragma unroll 16
  for (int t = 0; t < CHUNK; ++t) {
    unsigned int v = tile[t * 256 + tid];
    float br = bf2f((unsigned short)(v & 0xffffu));
    float bi = bf2f((unsigned short)(v >> 16));
    float nr = fmaf(l.x, xr, fmaf(-l.y, xi, br));
    float ni = fmaf(l.x, xi, fmaf(l.y, xr, bi));
    xr = nr; xi = ni;
    tile[t * 256 + tid] = (unsigned int)f2bf(xr) | ((unsigned int)f2bf(xi) << 16);
  }
  __syncthreads();
  unsigned int* obase = (unsigned int*)(xs + (size_t)chunk * CHUNK * N2P) + half * 256;
#pragma unroll
  for (int r = 0; r < 16; ++r) {
    int row = r * 4 + wave;
    *(u32x4*)(obase + (size_t)row * (N2P / 2) + lane * 4) =
        *(const u32x4*)(tile + row * 256 + lane * 4);
  }
}

// ---------------------------------------------------------------------------
extern "C" void kernel_launch(void* const* d_in, const int* in_sizes, int n_in,
                              void* d_out, int out_size, void* d_ws, size_t ws_size,
                              hipStream_t stream) {
  const float* U    = (const float*)d_in[0];
  const float* Lre  = (const float*)d_in[1];
  const float* Lim  = (const float*)d_in[2];
  const float* Bre  = (const float*)d_in[3];
  const float* Bim  = (const float*)d_in[4];
  const float* Cre  = (const float*)d_in[5];
  const float* Cim  = (const float*)d_in[6];
  const float* Dv   = (const float*)d_in[7];
  const float* lstp = (const float*)d_in[8];
  float* out = (float*)d_out;

  size_t off = 0;
  char* ws = (char*)d_ws;
  auto give = [&](size_t bytes) -> void* {
    void* p = ws + off;
    off += (bytes + 255) & ~(size_t)255;
    return p;
  };

  unsigned short* ubf  = (unsigned short*)give((size_t)L_SEQ * H_DIM * 2);  // 33.5 MB
  unsigned short* Bp   = (unsigned short*)give((size_t)N2P * H_DIM * 2);    //  2 MB
  unsigned short* Cp   = (unsigned short*)give((size_t)H_DIM * N2P * 2);    //  2 MB
  unsigned short* Bu   = (unsigned short*)give((size_t)L_SEQ * N2P * 2);    // 33.5 MB
  unsigned short* xs   = (unsigned short*)give((size_t)L_SEQ * N2P * 2);    // 33.5 MB
  float2*         lam  = (float2*)give(P_DIM * sizeof(float2));
  float2*         lamK = (float2*)give(P_DIM * sizeof(float2));
  unsigned long long* csum = (unsigned long long*)give((size_t)NCH * P_DIM * 8);
  int*            cnt  = (int*)give(256);

  k_pack_all<<<NB_U + NB_B + NB_C + NB_T, 256, 0, stream>>>(
      U, ubf, Bre, Bim, Bp, Cre, Cim, Cp, Lre, Lim, lstp, lam, lamK, cnt);

  gemm_bt<0><<<dim3(L_SEQ / 128, N2P / 128), 256, 0, stream>>>(ubf, Bp, Bu, nullptr, nullptr);

  k_scan<<<NCH * 2, 256, 0, stream>>>(Bu, lam, lamK, csum, cnt, xs);

  gemm_bt<1><<<dim3(L_SEQ / 128, N2P / 128), 256, 0, stream>>>(xs, Cp, out, ubf, Dv);
}

// Round 8
// 258.296 us; speedup vs baseline: 1.1008x; 1.1008x over previous
//
#include <hip/hip_runtime.h>
#include <stdint.h>
#include <stddef.h>

#define L_SEQ 16384
#define H_DIM 1024
#define P_DIM 512
#define N2P   1024
#define CHUNK 64
#define NCH   256   // L_SEQ / CHUNK

// merged pack-kernel block ranges
#define NB_U 8192   // L*H/(256*8)
#define NB_B 256    // P*H/(256*8)   -- vectorized 8 elems/thread
#define NB_C 512    // H*2P/(256*8)  -- vectorized 8 outs/thread
#define NB_T 2      // lambda tables

typedef __bf16 bf16x8 __attribute__((ext_vector_type(8)));
typedef float  f32x4  __attribute__((ext_vector_type(4)));
typedef unsigned short u16x8 __attribute__((ext_vector_type(8)));
typedef unsigned int   u32x4 __attribute__((ext_vector_type(4)));

__device__ __forceinline__ unsigned short f2bf(float x) {
  unsigned int u = __float_as_uint(x);
  u += 0x7FFFu + ((u >> 16) & 1u);   // round-to-nearest-even
  return (unsigned short)(u >> 16);
}
__device__ __forceinline__ float bf2f(unsigned short x) {
  return __uint_as_float((unsigned int)x << 16);
}

// ---------------------------------------------------------------------------
// Merged pack: [0,NB_U) u->bf16 cast; [NB_U,+NB_B) B_bar pack; then C pack;
// then lambda tables. All branches are block-uniform.
// Bp (2P,H): row 2p=Re, 2p+1=Im.  Cp (H,2P): col 2p=C_re, 2p+1=-C_im.
// ---------------------------------------------------------------------------
__global__ void k_pack_all(const float* __restrict__ U, unsigned short* __restrict__ Ub,
                           const float* __restrict__ Bre, const float* __restrict__ Bim,
                           unsigned short* __restrict__ Bp,
                           const float* __restrict__ Cre, const float* __restrict__ Cim,
                           unsigned short* __restrict__ Cp,
                           const float* __restrict__ Lre, const float* __restrict__ Lim,
                           const float* __restrict__ lstep,
                           float2* __restrict__ lam, float2* __restrict__ lamK) {
  int bid = blockIdx.x, tid = threadIdx.x;
  if (bid < NB_U) {
    size_t base = ((size_t)bid * 256 + tid) * 8;
    const float4* s = (const float4*)(U + base);
    float4 v0 = s[0], v1 = s[1];
    u16x8 o;
    o[0] = f2bf(v0.x); o[1] = f2bf(v0.y); o[2] = f2bf(v0.z); o[3] = f2bf(v0.w);
    o[4] = f2bf(v1.x); o[5] = f2bf(v1.y); o[6] = f2bf(v1.z); o[7] = f2bf(v1.w);
    *(u16x8*)(Ub + base) = o;
  } else if (bid < NB_U + NB_B) {
    // 8 elems/thread; base multiple of 8, so p = base>>10 is wave-uniform
    int base = ((bid - NB_U) * 256 + tid) * 8;       // < P*H
    int p = base >> 10, h = base & 1023;
    float sv, cv;
    float step = expf(lstep[p]);
    float ar = Lre[p] * step, ai = Lim[p] * step;
    float er = expf(ar);
    sincosf(ai, &sv, &cv);
    float lr = er * cv, li = er * sv;
    float nr = lr - 1.0f, ni = li;
    float dr = Lre[p], di = Lim[p];
    float den = dr * dr + di * di;
    float cx = (nr * dr + ni * di) / den;
    float cy = (ni * dr - nr * di) / den;
    const float4* sre = (const float4*)(Bre + base);
    const float4* sim = (const float4*)(Bim + base);
    float4 r0 = sre[0], r1 = sre[1], i0 = sim[0], i1 = sim[1];
    u16x8 ore, oim;
    ore[0] = f2bf(cx * r0.x - cy * i0.x);  oim[0] = f2bf(cx * i0.x + cy * r0.x);
    ore[1] = f2bf(cx * r0.y - cy * i0.y);  oim[1] = f2bf(cx * i0.y + cy * r0.y);
    ore[2] = f2bf(cx * r0.z - cy * i0.z);  oim[2] = f2bf(cx * i0.z + cy * r0.z);
    ore[3] = f2bf(cx * r0.w - cy * i0.w);  oim[3] = f2bf(cx * i0.w + cy * r0.w);
    ore[4] = f2bf(cx * r1.x - cy * i1.x);  oim[4] = f2bf(cx * i1.x + cy * r1.x);
    ore[5] = f2bf(cx * r1.y - cy * i1.y);  oim[5] = f2bf(cx * i1.y + cy * r1.y);
    ore[6] = f2bf(cx * r1.z - cy * i1.z);  oim[6] = f2bf(cx * i1.z + cy * r1.z);
    ore[7] = f2bf(cx * r1.w - cy * i1.w);  oim[7] = f2bf(cx * i1.w + cy * r1.w);
    *(u16x8*)(Bp + (size_t)(2 * p) * H_DIM + h)     = ore;
    *(u16x8*)(Bp + (size_t)(2 * p + 1) * H_DIM + h) = oim;
  } else if (bid < NB_U + NB_B + NB_C) {
    // 8 outputs/thread: row h of Cp, cols j0..j0+7 = p0..p0+3 interleaved re/-im
    int base = ((bid - NB_U - NB_B) * 256 + tid) * 8; // < H*2P
    int h = base >> 10, j0 = base & 1023;
    int p0 = j0 >> 1;                                 // multiple of 4
    float4 cr = *(const float4*)(Cre + (size_t)h * P_DIM + p0);
    float4 ci = *(const float4*)(Cim + (size_t)h * P_DIM + p0);
    u16x8 o;
    o[0] = f2bf(cr.x); o[1] = f2bf(-ci.x);
    o[2] = f2bf(cr.y); o[3] = f2bf(-ci.y);
    o[4] = f2bf(cr.z); o[5] = f2bf(-ci.z);
    o[6] = f2bf(cr.w); o[7] = f2bf(-ci.w);
    *(u16x8*)(Cp + base) = o;
  } else {
    int p = (bid - NB_U - NB_B - NB_C) * 256 + tid;
    if (p < P_DIM) {
      double step = exp((double)lstep[p]);
      double ar = (double)Lre[p] * step, ai = (double)Lim[p] * step;
      double er = exp(ar);
      lam[p] = make_float2((float)(er * cos(ai)), (float)(er * sin(ai)));
      double ka = (double)CHUNK * ai, kr = exp((double)CHUNK * ar);
      lamK[p] = make_float2((float)(kr * cos(ka)), (float)(kr * sin(ka)));
    }
  }
}

// ---------------------------------------------------------------------------
// GEMM: out(M,N) = A(M,K) @ B(N,K)^T, bf16 in. 128x128 tile, BK=64, 4 waves,
// 4x4 mfma_f32_16x16x32_bf16. Grid (M/128, N/128), blockIdx.x fastest =>
// all N-tiles of an M-panel on the same XCD (A-panel fetched once per chip).
// LDS XOR swizzle (row&7) on the 8-elem column group kills the 16-way bank
// aliasing of the plain BK=64 layout.
// OUT=0: bf16 store. OUT=1: fp32 store, fused 2*acc + Dv[col]*bf2f(Ub).
// ---------------------------------------------------------------------------
template <int OUT>
__global__ void gemm_bt(const unsigned short* __restrict__ A,
                        const unsigned short* __restrict__ B,
                        void* __restrict__ Cout,
                        const unsigned short* __restrict__ Ub,
                        const float* __restrict__ Dv) {
  const int K = 1024, N = 1024;
  __shared__ unsigned short sA[128 * 64];
  __shared__ unsigned short sB[128 * 64];
  const int tid = threadIdx.x;
  const int wave = tid >> 6, lane = tid & 63;
  const int quad = lane >> 4, l16 = lane & 15;
  const int m0 = blockIdx.x * 128, n0 = blockIdx.y * 128;
  const int wm = (wave & 1) * 64, wn = (wave >> 1) * 64;

  f32x4 acc[4][4] = {};

  for (int kt = 0; kt < K; kt += 64) {
    __syncthreads();
#pragma unroll
    for (int r = 0; r < 4; ++r) {
      int s = r * 256 + tid;                   // LDS slot = staging index
      int row = s >> 3;
      int j8 = (s & 7) ^ (row & 7);            // swizzled global column-group
      const unsigned short* ga = A + (size_t)(m0 + row) * K + kt + j8 * 8;
      const unsigned short* gb = B + (size_t)(n0 + row) * K + kt + j8 * 8;
      __builtin_amdgcn_global_load_lds(
          (const __attribute__((address_space(1))) unsigned int*)ga,
          (__attribute__((address_space(3))) unsigned int*)(sA + (r * 256 + wave * 64) * 8),
          16, 0, 0);
      __builtin_amdgcn_global_load_lds(
          (const __attribute__((address_space(1))) unsigned int*)gb,
          (__attribute__((address_space(3))) unsigned int*)(sB + (r * 256 + wave * 64) * 8),
          16, 0, 0);
    }
    __syncthreads();

#pragma unroll
    for (int h = 0; h < 2; ++h) {
      bf16x8 af[4], bfr[4];
#pragma unroll
      for (int i = 0; i < 4; ++i) {
        int ra = wm + i * 16 + l16;
        af[i] = *(const bf16x8*)(sA + ra * 64 + (((h << 2) + quad) ^ (ra & 7)) * 8);
      }
#pragma unroll
      for (int j = 0; j < 4; ++j) {
        int rb = wn + j * 16 + l16;
        bfr[j] = *(const bf16x8*)(sB + rb * 64 + (((h << 2) + quad) ^ (rb & 7)) * 8);
      }
#pragma unroll
      for (int i = 0; i < 4; ++i)
#pragma unroll
        for (int j = 0; j < 4; ++j)
          acc[i][j] = __builtin_amdgcn_mfma_f32_16x16x32_bf16(af[i], bfr[j], acc[i][j], 0, 0, 0);
    }
  }

#pragma unroll
  for (int i = 0; i < 4; ++i) {
#pragma unroll
    for (int j = 0; j < 4; ++j) {
      int col = n0 + wn + j * 16 + l16;
#pragma unroll
      for (int r = 0; r < 4; ++r) {
        int row = m0 + wm + i * 16 + quad * 4 + r;
        size_t o = (size_t)row * N + col;
        float v = acc[i][j][r];
        if (OUT) {
          float u = bf2f(Ub[o]);
          ((float*)Cout)[o] = 2.0f * v + Dv[col] * u;
        } else {
          ((unsigned short*)Cout)[o] = f2bf(v);
        }
      }
    }
  }
}

// ---------------------------------------------------------------------------
// Scan pass A, LDS-staged: block = (chunk, half). Stage 64 rows x 1024 B of
// Bu into LDS with full-row-contiguous global_load_lds sweeps, then scan
// columns out of LDS (bank = tid%32, constant in t, 2 lanes/bank = free).
// ---------------------------------------------------------------------------
__global__ __launch_bounds__(256) void k_scanA(const unsigned short* __restrict__ Bu,
                                               const float2* __restrict__ lam,
                                               float2* __restrict__ csum) {
  __shared__ unsigned int tile[CHUNK * 256];   // 64 KB
  const int bid = blockIdx.x;                  // NCH*2 blocks
  const int chunk = bid >> 1, half = bid & 1;
  const int tid = threadIdx.x, wave = tid >> 6, lane = tid & 63;
  const unsigned int* gbase =
      (const unsigned int*)(Bu + (size_t)chunk * CHUNK * N2P) + half * 256;
#pragma unroll
  for (int r = 0; r < 16; ++r) {
    int row = r * 4 + wave;
    __builtin_amdgcn_global_load_lds(
        (const __attribute__((address_space(1))) unsigned int*)
            (gbase + (size_t)row * (N2P / 2) + lane * 4),
        (__attribute__((address_space(3))) unsigned int*)(tile + row * 256),
        16, 0, 0);
  }
  __syncthreads();
  const int p = half * 256 + tid;
  const float2 l = lam[p];
  float xr = 0.f, xi = 0.f;
#pragma unroll 16
  for (int t = 0; t < CHUNK; ++t) {
    unsigned int v = tile[t * 256 + tid];
    float br = bf2f((unsigned short)(v & 0xffffu));
    float bi = bf2f((unsigned short)(v >> 16));
    float nr = fmaf(l.x, xr, fmaf(-l.y, xi, br));
    float ni = fmaf(l.x, xi, fmaf(l.y, xr, bi));
    xr = nr; xi = ni;
  }
  csum[(size_t)chunk * P_DIM + p] = make_float2(xr, xi);
}

// ---------------------------------------------------------------------------
// Scan pass C, LDS-staged, with Horner lookback over csum (L2-resident, loads
// independent; cross-kernel visibility via the kernel boundary). Stages the
// Bu tile, scans seeded with the carry, overwrites the tile in place with
// packed bf16 xs, then wide dwordx4 store phase.
// NOTE: xs aliases Bu (launcher). In-place is safe: each block's writes
// target exactly its own tile region, issued only after the whole tile is
// staged in LDS (__syncthreads), and blocks' regions are disjoint.
// ---------------------------------------------------------------------------
__global__ __launch_bounds__(256) void k_scanC(const unsigned short* __restrict__ Bu,
                                               const float2* __restrict__ lam,
                                               const float2* __restrict__ lamK,
                                               const float2* __restrict__ csum,
                                               unsigned short* __restrict__ xs) {
  __shared__ unsigned int tile[CHUNK * 256];   // 64 KB
  const int bid = blockIdx.x;
  const int chunk = bid >> 1, half = bid & 1;
  const int tid = threadIdx.x, wave = tid >> 6, lane = tid & 63;
  const unsigned int* gbase =
      (const unsigned int*)(Bu + (size_t)chunk * CHUNK * N2P) + half * 256;
#pragma unroll
  for (int r = 0; r < 16; ++r) {
    int row = r * 4 + wave;
    __builtin_amdgcn_global_load_lds(
        (const __attribute__((address_space(1))) unsigned int*)
            (gbase + (size_t)row * (N2P / 2) + lane * 4),
        (__attribute__((address_space(3))) unsigned int*)(tile + row * 256),
        16, 0, 0);
  }
  // lookback while the DMA is in flight
  const int p = half * 256 + tid;
  const float2 l = lam[p];
  const float2 lk = lamK[p];
  float cr = 0.f, ci = 0.f;
#pragma unroll 4
  for (int j = 0; j < chunk; ++j) {
    float2 s = csum[(size_t)j * P_DIM + p];
    float nr = fmaf(lk.x, cr, fmaf(-lk.y, ci, s.x));
    float ni = fmaf(lk.x, ci, fmaf(lk.y, cr, s.y));
    cr = nr; ci = ni;
  }
  __syncthreads();
  float xr = cr, xi = ci;
#pragma unroll 16
  for (int t = 0; t < CHUNK; ++t) {
    unsigned int v = tile[t * 256 + tid];
    float br = bf2f((unsigned short)(v & 0xffffu));
    float bi = bf2f((unsigned short)(v >> 16));
    float nr = fmaf(l.x, xr, fmaf(-l.y, xi, br));
    float ni = fmaf(l.x, xi, fmaf(l.y, xr, bi));
    xr = nr; xi = ni;
    tile[t * 256 + tid] = (unsigned int)f2bf(xr) | ((unsigned int)f2bf(xi) << 16);
  }
  __syncthreads();
  unsigned int* obase = (unsigned int*)(xs + (size_t)chunk * CHUNK * N2P) + half * 256;
#pragma unroll
  for (int r = 0; r < 16; ++r) {
    int row = r * 4 + wave;
    *(u32x4*)(obase + (size_t)row * (N2P / 2) + lane * 4) =
        *(const u32x4*)(tile + row * 256 + lane * 4);
  }
}

// ---------------------------------------------------------------------------
extern "C" void kernel_launch(void* const* d_in, const int* in_sizes, int n_in,
                              void* d_out, int out_size, void* d_ws, size_t ws_size,
                              hipStream_t stream) {
  const float* U    = (const float*)d_in[0];
  const float* Lre  = (const float*)d_in[1];
  const float* Lim  = (const float*)d_in[2];
  const float* Bre  = (const float*)d_in[3];
  const float* Bim  = (const float*)d_in[4];
  const float* Cre  = (const float*)d_in[5];
  const float* Cim  = (const float*)d_in[6];
  const float* Dv   = (const float*)d_in[7];
  const float* lstp = (const float*)d_in[8];
  float* out = (float*)d_out;

  size_t off = 0;
  char* ws = (char*)d_ws;
  auto give = [&](size_t bytes) -> void* {
    void* p = ws + off;
    off += (bytes + 255) & ~(size_t)255;
    return p;
  };

  // Workspace trimmed 105 MB -> ~72 MB: xs aliases Bu (scanC is in-place
  // safe; gemm1 runs after scanC). Tests whether the fixed ~70 us residue
  // scales with workspace size (harness re-poison traffic theory).
  unsigned short* ubf  = (unsigned short*)give((size_t)L_SEQ * H_DIM * 2);  // 33.5 MB
  unsigned short* Bp   = (unsigned short*)give((size_t)N2P * H_DIM * 2);    //  2 MB
  unsigned short* Cp   = (unsigned short*)give((size_t)H_DIM * N2P * 2);    //  2 MB
  unsigned short* Bu   = (unsigned short*)give((size_t)L_SEQ * N2P * 2);    // 33.5 MB
  float2*         lam  = (float2*)give(P_DIM * sizeof(float2));
  float2*         lamK = (float2*)give(P_DIM * sizeof(float2));
  float2*         csum = (float2*)give((size_t)NCH * P_DIM * sizeof(float2));
  unsigned short* xs   = Bu;   // alias

  k_pack_all<<<NB_U + NB_B + NB_C + NB_T, 256, 0, stream>>>(
      U, ubf, Bre, Bim, Bp, Cre, Cim, Cp, Lre, Lim, lstp, lam, lamK);

  gemm_bt<0><<<dim3(L_SEQ / 128, N2P / 128), 256, 0, stream>>>(ubf, Bp, Bu, nullptr, nullptr);

  k_scanA<<<NCH * 2, 256, 0, stream>>>(Bu, lam, csum);
  k_scanC<<<NCH * 2, 256, 0, stream>>>(Bu, lam, lamK, csum, xs);

  gemm_bt<1><<<dim3(L_SEQ / 128, N2P / 128), 256, 0, stream>>>(xs, Cp, out, ubf, Dv);
}